// Round 15
// baseline (312.478 us; speedup 1.0000x reference)
//
#include <hip/hip_runtime.h>
#include <hip/hip_bf16.h>
#include <math.h>
#include <stdint.h>

#define B_GRAPHS 64
#define N_NODES  2048
#define E_DIM    16
#define M_TOT    (B_GRAPHS * N_NODES)   // 131072
#define K_COND   64
#define MLP_IN   192
#define HID      512
#define POOLD    128
#define BN_EPS   1e-5f

typedef __attribute__((ext_vector_type(8))) short bfrag8;
typedef __attribute__((ext_vector_type(4))) float facc4;

__device__ __forceinline__ unsigned short f2b(float f) {
    unsigned int x = __builtin_bit_cast(unsigned int, f);
    unsigned int r = x + 0x7fffu + ((x >> 16) & 1u);
    return (unsigned short)(r >> 16);
}
__device__ __forceinline__ float b2f(unsigned short u) {
    unsigned int x = ((unsigned int)u) << 16;
    return __builtin_bit_cast(float, x);
}

// Branch-free GELU: erf via Abramowitz-Stegun 7.1.26 (|err| <= 1.5e-7).
__device__ __forceinline__ float gelu_fast(float y) {
    float x  = y * 0.70710678118654752440f;
    float ax = fabsf(x);
    float t  = __builtin_amdgcn_rcpf(fmaf(0.3275911f, ax, 1.0f));
    float p  = fmaf(1.061405429f, t, -1.453152027f);
    p = fmaf(p, t, 1.421413741f);
    p = fmaf(p, t, -0.284496736f);
    p = fmaf(p, t, 0.254829592f);
    p = p * t;
    float e = __expf(-x * x);
    float erfax = fmaf(-p, e, 1.0f);
    float erfx  = copysignf(erfax, x);
    return 0.5f * y * (1.0f + erfx);
}

#define GLOAD_LDS16(g, l)                                                        \
    __builtin_amdgcn_global_load_lds(                                            \
        (const __attribute__((address_space(1))) unsigned int*)(const void*)(g), \
        (__attribute__((address_space(3))) unsigned int*)(void*)(l), 16, 0, 0)

// ---------------- prep: pooled (LDS) -> gbias[g][n] = pooled . W1[n,64:192] + b1[n] ----------------
__global__ __launch_bounds__(512) void prep_kernel(const float* __restrict__ x,
                                                   const float* __restrict__ W1,
                                                   const float* __restrict__ b1,
                                                   float* __restrict__ gbias) {
    __shared__ float pl[POOLD];
    int g = blockIdx.x, t = threadIdx.x;
    if (t < 128) {
        int h = t >> 2, w = t & 3;
        const float* base = x + (size_t)g * N_NODES * E_DIM + (size_t)h * 64 * E_DIM + w * 4;
        float s = 0.f;
        #pragma unroll 4
        for (int r = 0; r < 64; ++r) {
            float4 v = *reinterpret_cast<const float4*>(base + (size_t)r * E_DIM);
            s += v.x + v.y + v.z + v.w;
        }
        pl[h * 4 + w] = s * (1.0f / 256.0f);
    }
    __syncthreads();
    const float* wr_ = W1 + (size_t)t * MLP_IN + K_COND;
    float s = b1[t];
    #pragma unroll 4
    for (int k = 0; k < POOLD; ++k) s = fmaf(pl[k], wr_[k], s);
    gbias[g * HID + t] = s;
}

// ------------- contiguous fp32 -> bf16 (for W2) -------------
__global__ __launch_bounds__(256) void cvt_kernel(const float* __restrict__ s,
                                                  unsigned short* __restrict__ d) {
    size_t i = ((size_t)blockIdx.x * 256 + threadIdx.x) * 8;
    float4 v0 = *reinterpret_cast<const float4*>(s + i);
    float4 v1 = *reinterpret_cast<const float4*>(s + i + 4);
    unsigned short t[8] = {f2b(v0.x), f2b(v0.y), f2b(v0.z), f2b(v0.w),
                           f2b(v1.x), f2b(v1.y), f2b(v1.z), f2b(v1.w)};
    *reinterpret_cast<bfrag8*>(d + i) = *reinterpret_cast<bfrag8*>(t);
}

__device__ __forceinline__ bfrag8 load_f32x8_as_bf16(const float* p) {
    float4 v0 = *reinterpret_cast<const float4*>(p);
    float4 v1 = *reinterpret_cast<const float4*>(p + 4);
    unsigned short t[8] = {f2b(v0.x), f2b(v0.y), f2b(v0.z), f2b(v0.w),
                           f2b(v1.x), f2b(v1.y), f2b(v1.z), f2b(v1.w)};
    return *reinterpret_cast<bfrag8*>(t);
}

// ------------- GEMM1: H1 = cond[.,0:64] @ W1[.,0:64]^T + gbias[row>>11], fused stats -------------
// (r9 verified) BM=128 x BN=512 full width, 8 waves, A staged once to LDS.
__global__ __launch_bounds__(512, 1) void gemm1_kernel(const float* __restrict__ A,
                                                       const float* __restrict__ W,
                                                       const float* __restrict__ gbias,
                                                       float* __restrict__ sums,
                                                       unsigned short* __restrict__ C) {
    __shared__ unsigned short As[128 * 64];      // 16KB, swizzled 16B granules
    __shared__ float sArr[HID], qArr[HID];
    const int t = threadIdx.x;
    const int r0 = blockIdx.x * 128;
    const int g = r0 >> 11;              // batch id (sorted repeat: row/2048)
    const int l = t & 63, w = t >> 6;
    const int wr = w >> 2, wc = w & 3;   // 2 x 4 waves
    const int ln = l & 15, kg = l >> 4;
    sArr[t] = 0.f; qArr[t] = 0.f;

    // stage cond block -> bf16 LDS (2 granules per thread)
    {
        const int cg = t & 7, rb = t >> 3;           // granule col, base row
        #pragma unroll
        for (int i = 0; i < 2; ++i) {
            int row = rb + i * 64;
            bfrag8 vv = load_f32x8_as_bf16(A + (size_t)(r0 + row) * K_COND + cg * 8);
            int dg = row * 8 + (cg ^ (row & 7));
            *reinterpret_cast<bfrag8*>(&As[dg * 8]) = vv;
        }
    }
    // B fragments for both K-steps (W1 fp32, inline cvt; L2-resident)
    bfrag8 bf0[8], bf1[8];
    #pragma unroll
    for (int b = 0; b < 8; ++b) {
        int RB = wc * 128 + b * 16 + ln;
        bf0[b] = load_f32x8_as_bf16(W + (size_t)RB * MLP_IN + kg * 8);
        bf1[b] = load_f32x8_as_bf16(W + (size_t)RB * MLP_IN + 32 + kg * 8);
    }
    __syncthreads();

    facc4 acc[4][8];
    const facc4 z = {0.f, 0.f, 0.f, 0.f};
    #pragma unroll
    for (int a = 0; a < 4; ++a)
        #pragma unroll
        for (int b = 0; b < 8; ++b) acc[a][b] = z;

    #pragma unroll
    for (int s = 0; s < 2; ++s) {
        bfrag8 af[4];
        #pragma unroll
        for (int a = 0; a < 4; ++a) {
            int RA = wr * 64 + a * 16 + ln;
            af[a] = *reinterpret_cast<const bfrag8*>(&As[(RA * 8 + ((s * 4 + kg) ^ (RA & 7))) * 8]);
        }
        #pragma unroll
        for (int a = 0; a < 4; ++a)
            #pragma unroll
            for (int b = 0; b < 8; ++b)
                acc[a][b] = __builtin_amdgcn_mfma_f32_16x16x32_bf16(
                    af[a], s == 0 ? bf0[b] : bf1[b], acc[a][b], 0, 0, 0);
    }

    const float* gb = gbias + (size_t)g * HID;
    float gbv[8];
    #pragma unroll
    for (int b = 0; b < 8; ++b) gbv[b] = gb[wc * 128 + b * 16 + ln];
    float cs[8], cq[8];
    #pragma unroll
    for (int b = 0; b < 8; ++b) { cs[b] = 0.f; cq[b] = 0.f; }
    #pragma unroll
    for (int a = 0; a < 4; ++a) {
        #pragma unroll
        for (int i = 0; i < 4; ++i) {
            size_t rbase = (size_t)(r0 + wr * 64 + a * 16 + kg * 4 + i) * HID + wc * 128 + ln;
            #pragma unroll
            for (int b = 0; b < 8; ++b) {
                float v = acc[a][b][i] + gbv[b];
                C[rbase + b * 16] = f2b(v);
                cs[b] += v; cq[b] = fmaf(v, v, cq[b]);
            }
        }
    }
    #pragma unroll
    for (int b = 0; b < 8; ++b) {
        cs[b] += __shfl_xor(cs[b], 16, 64); cq[b] += __shfl_xor(cq[b], 16, 64);
        cs[b] += __shfl_xor(cs[b], 32, 64); cq[b] += __shfl_xor(cq[b], 32, 64);
    }
    if (kg == 0) {
        #pragma unroll
        for (int b = 0; b < 8; ++b) {
            int cl = wc * 128 + b * 16 + ln;
            atomicAdd(&sArr[cl], cs[b]); atomicAdd(&qArr[cl], cq[b]);
        }
    }
    __syncthreads();
    atomicAdd(&sums[t], sArr[t]);
    atomicAdd(&sums[HID + t], qArr[t]);
}

// ------------- finalize: ss[0:512]=scale, ss[512:1024]=shift -------------
__global__ void finalize_kernel(const float* __restrict__ sums, const float* __restrict__ g,
                                const float* __restrict__ be, float* __restrict__ ss) {
    int n = threadIdx.x;  // 512
    float mean = sums[n] * (1.0f / M_TOT);
    float var = sums[HID + n] * (1.0f / M_TOT) - mean * mean;
    float sc = g[n] * rsqrtf(var + BN_EPS);
    ss[n] = sc;
    ss[HID + n] = be[n] - mean * sc;
}

// ------------- act: H = gelu(H*scale+shift) in place (bf16), grid-stride -------------
#define ACT_BLOCKS 2048
__global__ __launch_bounds__(256) void act_kernel(unsigned short* __restrict__ H,
                                                  const float* __restrict__ ss) {
    __shared__ float lss[2 * HID];
    int t = threadIdx.x;
    #pragma unroll
    for (int i = t; i < 2 * HID; i += 256) lss[i] = ss[i];
    __syncthreads();
    size_t gi = (size_t)blockIdx.x * 256 + t;           // granule index (8 elems)
    const size_t stride = (size_t)ACT_BLOCKS * 256;
    #pragma unroll
    for (int it = 0; it < 16; ++it, gi += stride) {
        size_t idx = gi * 8;
        int col = (int)(idx & (HID - 1));
        bfrag8 v = *reinterpret_cast<bfrag8*>(&H[idx]);
        #pragma unroll
        for (int j = 0; j < 8; ++j) {
            float x = b2f((unsigned short)v[j]);
            float y = fmaf(x, lss[col + j], lss[HID + col + j]);
            y = gelu_fast(y);
            v[j] = (short)f2b(y);
        }
        *reinterpret_cast<bfrag8*>(&H[idx]) = v;
    }
}

// ------------- GEMM2: H2 = H1act @ W2^T + b2, fused stats2 -------------
// r14 structure (121us, conflicts 0, FETCH 74MB via XCD-affine remap) with ONE
// parameter change: BK=64 (kh-loop over two identical 32-halves) -> half the
// barrier pairs, 2x staged bytes per drain. LDS 33KB, VGPR ~84 unchanged.
__global__ __launch_bounds__(256) void gemm2_kernel(const unsigned short* __restrict__ A,
                                                    const unsigned short* __restrict__ Bm,
                                                    const float* __restrict__ bias,
                                                    float* __restrict__ sums,
                                                    unsigned short* __restrict__ C) {
    __shared__ unsigned short As[2 * 128 * 32];  // [kh][row][32] 16KB
    __shared__ unsigned short Bs[2 * 128 * 32];  // 16KB
    __shared__ float sArr[128], qArr[128];       // 1KB
    const int d = blockIdx.x;                    // 4096 dispatches
    const int xcd = d & 7, slot = d >> 3;
    const int cb = slot & 3, rhi = slot >> 2;    // rhi in [0,128)
    const int rb = (rhi << 3) | xcd;             // rb in [0,1024), bijective
    const int r0 = rb * 128, c0 = cb * 128;
    const int t = threadIdx.x;
    const int l = t & 63, w = t >> 6;            // 4 waves
    const int wr = w >> 1, wc = w & 1;           // 2 x 2; wave tile 64 x 64
    const int ln = l & 15, kg = l >> 4;
    const int rr = l >> 2, sp = l & 3;
    const int bss = sp ^ ((rr >> 1) & 3);        // pre-swizzled source slot
    if (t < 128) { sArr[t] = 0.f; qArr[t] = 0.f; }

    facc4 acc[4][4];
    const facc4 z = {0.f, 0.f, 0.f, 0.f};
    #pragma unroll
    for (int a = 0; a < 4; ++a)
        #pragma unroll
        for (int b = 0; b < 4; ++b) acc[a][b] = z;

    for (int kk = 0; kk < HID; kk += 64) {
        #pragma unroll
        for (int kh = 0; kh < 2; ++kh) {
            #pragma unroll
            for (int c = 0; c < 2; ++c) {
                const int chunk = w * 2 + c;      // 8 chunks x 16 rows per half
                const unsigned short* ga =
                    A + (size_t)(r0 + chunk * 16 + rr) * HID + kk + kh * 32 + bss * 8;
                GLOAD_LDS16(ga, &As[kh * 4096 + chunk * 512]);
                const unsigned short* gb =
                    Bm + (size_t)(c0 + chunk * 16 + rr) * HID + kk + kh * 32 + bss * 8;
                GLOAD_LDS16(gb, &Bs[kh * 4096 + chunk * 512]);
            }
        }
        __syncthreads();
        #pragma unroll
        for (int kh = 0; kh < 2; ++kh) {
            bfrag8 af[4], bf[4];
            #pragma unroll
            for (int a = 0; a < 4; ++a) {
                int RA = wr * 64 + a * 16 + ln;
                af[a] = *reinterpret_cast<const bfrag8*>(
                    &As[kh * 4096 + RA * 32 + (kg ^ ((RA >> 1) & 3)) * 8]);
            }
            #pragma unroll
            for (int b = 0; b < 4; ++b) {
                int RB = wc * 64 + b * 16 + ln;
                bf[b] = *reinterpret_cast<const bfrag8*>(
                    &Bs[kh * 4096 + RB * 32 + (kg ^ ((RB >> 1) & 3)) * 8]);
            }
            #pragma unroll
            for (int a = 0; a < 4; ++a)
                #pragma unroll
                for (int b = 0; b < 4; ++b)
                    acc[a][b] = __builtin_amdgcn_mfma_f32_16x16x32_bf16(af[a], bf[b], acc[a][b], 0, 0, 0);
        }
        __syncthreads();
    }

    float bb[4];
    #pragma unroll
    for (int b = 0; b < 4; ++b) bb[b] = bias[c0 + wc * 64 + b * 16 + ln];
    float cs[4] = {0.f, 0.f, 0.f, 0.f}, cq[4] = {0.f, 0.f, 0.f, 0.f};
    #pragma unroll
    for (int a = 0; a < 4; ++a) {
        #pragma unroll
        for (int i = 0; i < 4; ++i) {
            size_t rbase = (size_t)(r0 + wr * 64 + a * 16 + kg * 4 + i) * HID + c0 + wc * 64 + ln;
            #pragma unroll
            for (int b = 0; b < 4; ++b) {
                float v = acc[a][b][i] + bb[b];
                C[rbase + b * 16] = f2b(v);
                cs[b] += v; cq[b] = fmaf(v, v, cq[b]);
            }
        }
    }
    #pragma unroll
    for (int b = 0; b < 4; ++b) {
        cs[b] += __shfl_xor(cs[b], 16, 64); cq[b] += __shfl_xor(cq[b], 16, 64);
        cs[b] += __shfl_xor(cs[b], 32, 64); cq[b] += __shfl_xor(cq[b], 32, 64);
    }
    if (kg == 0) {
        #pragma unroll
        for (int b = 0; b < 4; ++b) {
            int cl = wc * 64 + b * 16 + ln;
            atomicAdd(&sArr[cl], cs[b]); atomicAdd(&qArr[cl], cq[b]);
        }
    }
    __syncthreads();
    if (t < 128) {
        atomicAdd(&sums[c0 + t], sArr[t]);
        atomicAdd(&sums[HID + c0 + t], qArr[t]);
    }
}

// ------------- G3: out[m][0:3] = gelu(bn2(H2[m])) . W3^T + b3  (8 lanes per row) -------------
__global__ __launch_bounds__(256) void g3_kernel(const unsigned short* __restrict__ H2,
                                                 const float* __restrict__ ss2,
                                                 const float* __restrict__ W3,
                                                 const float* __restrict__ b3,
                                                 float* __restrict__ out) {
    __shared__ float lss[2 * HID];
    __shared__ float lw3[3 * HID];
    int t = threadIdx.x;
    for (int i = t; i < 2 * HID; i += 256) lss[i] = ss2[i];
    for (int i = t; i < 3 * HID; i += 256) lw3[i] = W3[i];
    __syncthreads();
    int l = t & 63, w = t >> 6;
    int rsub = l >> 3, lk = l & 7;
    int row = blockIdx.x * 32 + w * 8 + rsub;
    const unsigned short* p = H2 + (size_t)row * HID;
    float o0 = 0.f, o1 = 0.f, o2 = 0.f;
    #pragma unroll
    for (int it = 0; it < 8; ++it) {
        int k = it * 64 + lk * 8;
        bfrag8 v = *reinterpret_cast<const bfrag8*>(p + k);
        #pragma unroll
        for (int j = 0; j < 8; ++j) {
            float x = b2f((unsigned short)v[j]);
            float y = fmaf(x, lss[k + j], lss[HID + k + j]);
            y = gelu_fast(y);
            o0 = fmaf(y, lw3[k + j], o0);
            o1 = fmaf(y, lw3[HID + k + j], o1);
            o2 = fmaf(y, lw3[2 * HID + k + j], o2);
        }
    }
    #pragma unroll
    for (int m = 1; m < 8; m <<= 1) {
        o0 += __shfl_xor(o0, m, 64);
        o1 += __shfl_xor(o1, m, 64);
        o2 += __shfl_xor(o2, m, 64);
    }
    if (lk == 0) {
        out[(size_t)row * 3 + 0] = o0 + b3[0];
        out[(size_t)row * 3 + 1] = o1 + b3[1];
        out[(size_t)row * 3 + 2] = o2 + b3[2];
    }
}

extern "C" void kernel_launch(void* const* d_in, const int* in_sizes, int n_in,
                              void* d_out, int out_size, void* d_ws, size_t ws_size,
                              hipStream_t stream) {
    const float* x     = (const float*)d_in[0];
    const float* cond  = (const float*)d_in[2];
    const float* W1    = (const float*)d_in[3];
    const float* b1    = (const float*)d_in[4];
    const float* g1    = (const float*)d_in[5];
    const float* be1   = (const float*)d_in[6];
    const float* W2    = (const float*)d_in[7];
    const float* b2    = (const float*)d_in[8];
    const float* g2    = (const float*)d_in[9];
    const float* be2   = (const float*)d_in[10];
    const float* W3    = (const float*)d_in[11];
    const float* b3    = (const float*)d_in[12];

    const size_t H_BYTES = (size_t)M_TOT * HID * 2;  // 134,217,728
    if (ws_size < 2 * H_BYTES) return;               // clean fail instead of OOB crash
    char* ws = (char*)d_ws;
    unsigned short* H1 = (unsigned short*)ws;
    unsigned short* H2 = (unsigned short*)(ws + H_BYTES);

    // Small scratch lives in d_out (1.57MB) until g3 overwrites it.
    float* outf   = (float*)d_out;
    float* gbias  = outf;                        // 32768 floats
    float* sums1  = gbias + B_GRAPHS * HID;      // 1024 (sum | sumsq)
    float* sums2  = sums1 + 2 * HID;             // 1024
    float* ss1    = sums2 + 2 * HID;             // 1024
    unsigned short* W2bf = (unsigned short*)(ss1 + 2 * HID);  // 262144 shorts (512KB)
    // ss2 lives in the H1 region: written by finalize2 AFTER gemm2 consumed H1,
    // read by g3 (which writes d_out — so it can't live in d_out).
    float* ss2 = (float*)ws;

    hipMemsetAsync(sums1, 0, 2 * 2 * HID * sizeof(float), stream);

    prep_kernel<<<B_GRAPHS, 512, 0, stream>>>(x, W1, b1, gbias);
    cvt_kernel<<<(HID * HID / 8) / 256, 256, 0, stream>>>(W2, W2bf);

    gemm1_kernel<<<dim3(M_TOT / 128, 1), 512, 0, stream>>>(
        cond, W1, gbias, sums1, H1);
    finalize_kernel<<<1, HID, 0, stream>>>(sums1, g1, be1, ss1);
    act_kernel<<<ACT_BLOCKS, 256, 0, stream>>>(H1, ss1);

    gemm2_kernel<<<(M_TOT / 128) * (HID / 128), 256, 0, stream>>>(
        H1, W2bf, b2, sums2, H2);
    finalize_kernel<<<1, HID, 0, stream>>>(sums2, g2, be2, ss2);

    g3_kernel<<<M_TOT / 32, 256, 0, stream>>>(H2, ss2, W3, b3, outf);
}

// Round 16
// 296.060 us; speedup vs baseline: 1.0555x; 1.0555x over previous
//
#include <hip/hip_runtime.h>
#include <hip/hip_bf16.h>
#include <math.h>
#include <stdint.h>

#define B_GRAPHS 64
#define N_NODES  2048
#define E_DIM    16
#define M_TOT    (B_GRAPHS * N_NODES)   // 131072
#define K_COND   64
#define MLP_IN   192
#define HID      512
#define POOLD    128
#define BN_EPS   1e-5f

typedef __attribute__((ext_vector_type(8))) short bfrag8;
typedef __attribute__((ext_vector_type(4))) float facc4;

__device__ __forceinline__ unsigned short f2b(float f) {
    unsigned int x = __builtin_bit_cast(unsigned int, f);
    unsigned int r = x + 0x7fffu + ((x >> 16) & 1u);
    return (unsigned short)(r >> 16);
}
__device__ __forceinline__ float b2f(unsigned short u) {
    unsigned int x = ((unsigned int)u) << 16;
    return __builtin_bit_cast(float, x);
}

// Branch-free GELU: erf via Abramowitz-Stegun 7.1.26 (|err| <= 1.5e-7).
__device__ __forceinline__ float gelu_fast(float y) {
    float x  = y * 0.70710678118654752440f;
    float ax = fabsf(x);
    float t  = __builtin_amdgcn_rcpf(fmaf(0.3275911f, ax, 1.0f));
    float p  = fmaf(1.061405429f, t, -1.453152027f);
    p = fmaf(p, t, 1.421413741f);
    p = fmaf(p, t, -0.284496736f);
    p = fmaf(p, t, 0.254829592f);
    p = p * t;
    float e = __expf(-x * x);
    float erfax = fmaf(-p, e, 1.0f);
    float erfx  = copysignf(erfax, x);
    return 0.5f * y * (1.0f + erfx);
}

#define GLOAD_LDS16(g, l)                                                        \
    __builtin_amdgcn_global_load_lds(                                            \
        (const __attribute__((address_space(1))) unsigned int*)(const void*)(g), \
        (__attribute__((address_space(3))) unsigned int*)(void*)(l), 16, 0, 0)

// ---------------- prep: pooled (LDS) -> gbias[g][n] = pooled . W1[n,64:192] + b1[n] ----------------
__global__ __launch_bounds__(512) void prep_kernel(const float* __restrict__ x,
                                                   const float* __restrict__ W1,
                                                   const float* __restrict__ b1,
                                                   float* __restrict__ gbias) {
    __shared__ float pl[POOLD];
    int g = blockIdx.x, t = threadIdx.x;
    if (t < 128) {
        int h = t >> 2, w = t & 3;
        const float* base = x + (size_t)g * N_NODES * E_DIM + (size_t)h * 64 * E_DIM + w * 4;
        float s = 0.f;
        #pragma unroll 4
        for (int r = 0; r < 64; ++r) {
            float4 v = *reinterpret_cast<const float4*>(base + (size_t)r * E_DIM);
            s += v.x + v.y + v.z + v.w;
        }
        pl[h * 4 + w] = s * (1.0f / 256.0f);
    }
    __syncthreads();
    const float* wr_ = W1 + (size_t)t * MLP_IN + K_COND;
    float s = b1[t];
    #pragma unroll 4
    for (int k = 0; k < POOLD; ++k) s = fmaf(pl[k], wr_[k], s);
    gbias[g * HID + t] = s;
}

// ------------- contiguous fp32 -> bf16 (for W2) -------------
__global__ __launch_bounds__(256) void cvt_kernel(const float* __restrict__ s,
                                                  unsigned short* __restrict__ d) {
    size_t i = ((size_t)blockIdx.x * 256 + threadIdx.x) * 8;
    float4 v0 = *reinterpret_cast<const float4*>(s + i);
    float4 v1 = *reinterpret_cast<const float4*>(s + i + 4);
    unsigned short t[8] = {f2b(v0.x), f2b(v0.y), f2b(v0.z), f2b(v0.w),
                           f2b(v1.x), f2b(v1.y), f2b(v1.z), f2b(v1.w)};
    *reinterpret_cast<bfrag8*>(d + i) = *reinterpret_cast<bfrag8*>(t);
}

__device__ __forceinline__ bfrag8 load_f32x8_as_bf16(const float* p) {
    float4 v0 = *reinterpret_cast<const float4*>(p);
    float4 v1 = *reinterpret_cast<const float4*>(p + 4);
    unsigned short t[8] = {f2b(v0.x), f2b(v0.y), f2b(v0.z), f2b(v0.w),
                           f2b(v1.x), f2b(v1.y), f2b(v1.z), f2b(v1.w)};
    return *reinterpret_cast<bfrag8*>(t);
}

// ------------- GEMM1: H1 = cond[.,0:64] @ W1[.,0:64]^T + gbias[row>>11], fused stats -------------
// r14-gemm2 geometry applied to gemm1: 256 threads / 4 waves (2x2), BM=BN=128,
// grid 4096 with XCD-affine remap (cond re-reads x4 hit home L2), acc[4][4],
// K=64 in 2 steps; cond LDS-staged (r9-verified swizzle), W1 frags reg-loaded.
__global__ __launch_bounds__(256) void gemm1_kernel(const float* __restrict__ A,
                                                    const float* __restrict__ W,
                                                    const float* __restrict__ gbias,
                                                    float* __restrict__ sums,
                                                    unsigned short* __restrict__ C) {
    __shared__ unsigned short As[128 * 64];      // 16KB, swizzled 16B granules
    __shared__ float sArr[128], qArr[128];       // 1KB
    const int d = blockIdx.x;                    // 4096 dispatches
    const int xcd = d & 7, slot = d >> 3;
    const int cb = slot & 3, rhi = slot >> 2;    // rhi in [0,128)
    const int rb = (rhi << 3) | xcd;             // rb in [0,1024), bijective
    const int r0 = rb * 128, c0 = cb * 128;
    const int g = r0 >> 11;                      // batch id (sorted repeat)
    const int t = threadIdx.x;
    const int l = t & 63, w = t >> 6;            // 4 waves
    const int wr = w >> 1, wc = w & 1;           // 2 x 2; wave tile 64 x 64
    const int ln = l & 15, kg = l >> 4;
    if (t < 128) { sArr[t] = 0.f; qArr[t] = 0.f; }

    // stage cond block -> bf16 LDS (4 granules per thread; granule grid 128x8)
    {
        const int cg = t & 7, rbase_ = t >> 3;   // granule col, base row (0..31)
        #pragma unroll
        for (int i = 0; i < 4; ++i) {
            int row = rbase_ + i * 32;
            bfrag8 vv = load_f32x8_as_bf16(A + (size_t)(r0 + row) * K_COND + cg * 8);
            int dg = row * 8 + (cg ^ (row & 7));
            *reinterpret_cast<bfrag8*>(&As[dg * 8]) = vv;
        }
    }
    // W1 fragments for both K-steps (fp32, inline cvt; L2-resident slice)
    bfrag8 bf0[4], bf1[4];
    #pragma unroll
    for (int b = 0; b < 4; ++b) {
        int RB = c0 + wc * 64 + b * 16 + ln;
        bf0[b] = load_f32x8_as_bf16(W + (size_t)RB * MLP_IN + kg * 8);
        bf1[b] = load_f32x8_as_bf16(W + (size_t)RB * MLP_IN + 32 + kg * 8);
    }
    __syncthreads();

    facc4 acc[4][4];
    const facc4 z = {0.f, 0.f, 0.f, 0.f};
    #pragma unroll
    for (int a = 0; a < 4; ++a)
        #pragma unroll
        for (int b = 0; b < 4; ++b) acc[a][b] = z;

    #pragma unroll
    for (int s = 0; s < 2; ++s) {
        bfrag8 af[4];
        #pragma unroll
        for (int a = 0; a < 4; ++a) {
            int RA = wr * 64 + a * 16 + ln;
            af[a] = *reinterpret_cast<const bfrag8*>(&As[(RA * 8 + ((s * 4 + kg) ^ (RA & 7))) * 8]);
        }
        #pragma unroll
        for (int a = 0; a < 4; ++a)
            #pragma unroll
            for (int b = 0; b < 4; ++b)
                acc[a][b] = __builtin_amdgcn_mfma_f32_16x16x32_bf16(
                    af[a], s == 0 ? bf0[b] : bf1[b], acc[a][b], 0, 0, 0);
    }

    const float* gb = gbias + (size_t)g * HID;
    float gbv[4];
    #pragma unroll
    for (int b = 0; b < 4; ++b) gbv[b] = gb[c0 + wc * 64 + b * 16 + ln];
    float cs[4] = {0.f, 0.f, 0.f, 0.f}, cq[4] = {0.f, 0.f, 0.f, 0.f};
    #pragma unroll
    for (int a = 0; a < 4; ++a) {
        #pragma unroll
        for (int i = 0; i < 4; ++i) {
            size_t rbase = (size_t)(r0 + wr * 64 + a * 16 + kg * 4 + i) * HID + c0 + wc * 64 + ln;
            #pragma unroll
            for (int b = 0; b < 4; ++b) {
                float v = acc[a][b][i] + gbv[b];
                C[rbase + b * 16] = f2b(v);
                cs[b] += v; cq[b] = fmaf(v, v, cq[b]);
            }
        }
    }
    #pragma unroll
    for (int b = 0; b < 4; ++b) {
        cs[b] += __shfl_xor(cs[b], 16, 64); cq[b] += __shfl_xor(cq[b], 16, 64);
        cs[b] += __shfl_xor(cs[b], 32, 64); cq[b] += __shfl_xor(cq[b], 32, 64);
    }
    if (kg == 0) {
        #pragma unroll
        for (int b = 0; b < 4; ++b) {
            int cl = wc * 64 + b * 16 + ln;
            atomicAdd(&sArr[cl], cs[b]); atomicAdd(&qArr[cl], cq[b]);
        }
    }
    __syncthreads();
    if (t < 128) {
        atomicAdd(&sums[c0 + t], sArr[t]);
        atomicAdd(&sums[HID + c0 + t], qArr[t]);
    }
}

// ------------- finalize: ss[0:512]=scale, ss[512:1024]=shift -------------
__global__ void finalize_kernel(const float* __restrict__ sums, const float* __restrict__ g,
                                const float* __restrict__ be, float* __restrict__ ss) {
    int n = threadIdx.x;  // 512
    float mean = sums[n] * (1.0f / M_TOT);
    float var = sums[HID + n] * (1.0f / M_TOT) - mean * mean;
    float sc = g[n] * rsqrtf(var + BN_EPS);
    ss[n] = sc;
    ss[HID + n] = be[n] - mean * sc;
}

// ------------- act: H = gelu(H*scale+shift) in place (bf16), grid-stride -------------
#define ACT_BLOCKS 2048
__global__ __launch_bounds__(256) void act_kernel(unsigned short* __restrict__ H,
                                                  const float* __restrict__ ss) {
    __shared__ float lss[2 * HID];
    int t = threadIdx.x;
    #pragma unroll
    for (int i = t; i < 2 * HID; i += 256) lss[i] = ss[i];
    __syncthreads();
    size_t gi = (size_t)blockIdx.x * 256 + t;           // granule index (8 elems)
    const size_t stride = (size_t)ACT_BLOCKS * 256;
    #pragma unroll
    for (int it = 0; it < 16; ++it, gi += stride) {
        size_t idx = gi * 8;
        int col = (int)(idx & (HID - 1));
        bfrag8 v = *reinterpret_cast<bfrag8*>(&H[idx]);
        #pragma unroll
        for (int j = 0; j < 8; ++j) {
            float x = b2f((unsigned short)v[j]);
            float y = fmaf(x, lss[col + j], lss[HID + col + j]);
            y = gelu_fast(y);
            v[j] = (short)f2b(y);
        }
        *reinterpret_cast<bfrag8*>(&H[idx]) = v;
    }
}

// ------------- GEMM2: H2 = H1act @ W2^T + b2, fused stats2 -------------
// r14 verbatim (121.5us measured): BK=32, 17KB LDS, VGPR 84, 2-3 blocks/CU,
// XOR-granule swizzle (conflicts 0), XCD-affine remap (FETCH 74MB).
__global__ __launch_bounds__(256) void gemm2_kernel(const unsigned short* __restrict__ A,
                                                    const unsigned short* __restrict__ Bm,
                                                    const float* __restrict__ bias,
                                                    float* __restrict__ sums,
                                                    unsigned short* __restrict__ C) {
    __shared__ unsigned short As[128 * 32];      // 8KB
    __shared__ unsigned short Bs[128 * 32];      // 8KB
    __shared__ float sArr[128], qArr[128];       // 1KB
    const int d = blockIdx.x;                    // 4096 dispatches
    const int xcd = d & 7, slot = d >> 3;
    const int cb = slot & 3, rhi = slot >> 2;    // rhi in [0,128)
    const int rb = (rhi << 3) | xcd;             // rb in [0,1024), bijective
    const int r0 = rb * 128, c0 = cb * 128;
    const int t = threadIdx.x;
    const int l = t & 63, w = t >> 6;            // 4 waves
    const int wr = w >> 1, wc = w & 1;           // 2 x 2; wave tile 64 x 64
    const int ln = l & 15, kg = l >> 4;
    const int rr = l >> 2, sp = l & 3;
    const int bss = sp ^ ((rr >> 1) & 3);        // pre-swizzled source slot
    if (t < 128) { sArr[t] = 0.f; qArr[t] = 0.f; }

    facc4 acc[4][4];
    const facc4 z = {0.f, 0.f, 0.f, 0.f};
    #pragma unroll
    for (int a = 0; a < 4; ++a)
        #pragma unroll
        for (int b = 0; b < 4; ++b) acc[a][b] = z;

    for (int kk = 0; kk < HID; kk += 32) {
        #pragma unroll
        for (int c = 0; c < 2; ++c) {
            const int chunk = w * 2 + c;          // 8 chunks x 16 rows
            const unsigned short* ga = A + (size_t)(r0 + chunk * 16 + rr) * HID + kk + bss * 8;
            GLOAD_LDS16(ga, &As[chunk * 512]);
            const unsigned short* gb = Bm + (size_t)(c0 + chunk * 16 + rr) * HID + kk + bss * 8;
            GLOAD_LDS16(gb, &Bs[chunk * 512]);
        }
        __syncthreads();
        bfrag8 af[4], bf[4];
        #pragma unroll
        for (int a = 0; a < 4; ++a) {
            int RA = wr * 64 + a * 16 + ln;
            af[a] = *reinterpret_cast<const bfrag8*>(&As[RA * 32 + (kg ^ ((RA >> 1) & 3)) * 8]);
        }
        #pragma unroll
        for (int b = 0; b < 4; ++b) {
            int RB = wc * 64 + b * 16 + ln;
            bf[b] = *reinterpret_cast<const bfrag8*>(&Bs[RB * 32 + (kg ^ ((RB >> 1) & 3)) * 8]);
        }
        #pragma unroll
        for (int a = 0; a < 4; ++a)
            #pragma unroll
            for (int b = 0; b < 4; ++b)
                acc[a][b] = __builtin_amdgcn_mfma_f32_16x16x32_bf16(af[a], bf[b], acc[a][b], 0, 0, 0);
        __syncthreads();
    }

    float bb[4];
    #pragma unroll
    for (int b = 0; b < 4; ++b) bb[b] = bias[c0 + wc * 64 + b * 16 + ln];
    float cs[4] = {0.f, 0.f, 0.f, 0.f}, cq[4] = {0.f, 0.f, 0.f, 0.f};
    #pragma unroll
    for (int a = 0; a < 4; ++a) {
        #pragma unroll
        for (int i = 0; i < 4; ++i) {
            size_t rbase = (size_t)(r0 + wr * 64 + a * 16 + kg * 4 + i) * HID + c0 + wc * 64 + ln;
            #pragma unroll
            for (int b = 0; b < 4; ++b) {
                float v = acc[a][b][i] + bb[b];
                C[rbase + b * 16] = f2b(v);
                cs[b] += v; cq[b] = fmaf(v, v, cq[b]);
            }
        }
    }
    #pragma unroll
    for (int b = 0; b < 4; ++b) {
        cs[b] += __shfl_xor(cs[b], 16, 64); cq[b] += __shfl_xor(cq[b], 16, 64);
        cs[b] += __shfl_xor(cs[b], 32, 64); cq[b] += __shfl_xor(cq[b], 32, 64);
    }
    if (kg == 0) {
        #pragma unroll
        for (int b = 0; b < 4; ++b) {
            int cl = wc * 64 + b * 16 + ln;
            atomicAdd(&sArr[cl], cs[b]); atomicAdd(&qArr[cl], cq[b]);
        }
    }
    __syncthreads();
    if (t < 128) {
        atomicAdd(&sums[c0 + t], sArr[t]);
        atomicAdd(&sums[HID + c0 + t], qArr[t]);
    }
}

// ------------- G3: out[m][0:3] = gelu(bn2(H2[m])) . W3^T + b3  (8 lanes per row) -------------
__global__ __launch_bounds__(256) void g3_kernel(const unsigned short* __restrict__ H2,
                                                 const float* __restrict__ ss2,
                                                 const float* __restrict__ W3,
                                                 const float* __restrict__ b3,
                                                 float* __restrict__ out) {
    __shared__ float lss[2 * HID];
    __shared__ float lw3[3 * HID];
    int t = threadIdx.x;
    for (int i = t; i < 2 * HID; i += 256) lss[i] = ss2[i];
    for (int i = t; i < 3 * HID; i += 256) lw3[i] = W3[i];
    __syncthreads();
    int l = t & 63, w = t >> 6;
    int rsub = l >> 3, lk = l & 7;
    int row = blockIdx.x * 32 + w * 8 + rsub;
    const unsigned short* p = H2 + (size_t)row * HID;
    float o0 = 0.f, o1 = 0.f, o2 = 0.f;
    #pragma unroll
    for (int it = 0; it < 8; ++it) {
        int k = it * 64 + lk * 8;
        bfrag8 v = *reinterpret_cast<const bfrag8*>(p + k);
        #pragma unroll
        for (int j = 0; j < 8; ++j) {
            float x = b2f((unsigned short)v[j]);
            float y = fmaf(x, lss[k + j], lss[HID + k + j]);
            y = gelu_fast(y);
            o0 = fmaf(y, lw3[k + j], o0);
            o1 = fmaf(y, lw3[HID + k + j], o1);
            o2 = fmaf(y, lw3[2 * HID + k + j], o2);
        }
    }
    #pragma unroll
    for (int m = 1; m < 8; m <<= 1) {
        o0 += __shfl_xor(o0, m, 64);
        o1 += __shfl_xor(o1, m, 64);
        o2 += __shfl_xor(o2, m, 64);
    }
    if (lk == 0) {
        out[(size_t)row * 3 + 0] = o0 + b3[0];
        out[(size_t)row * 3 + 1] = o1 + b3[1];
        out[(size_t)row * 3 + 2] = o2 + b3[2];
    }
}

extern "C" void kernel_launch(void* const* d_in, const int* in_sizes, int n_in,
                              void* d_out, int out_size, void* d_ws, size_t ws_size,
                              hipStream_t stream) {
    const float* x     = (const float*)d_in[0];
    const float* cond  = (const float*)d_in[2];
    const float* W1    = (const float*)d_in[3];
    const float* b1    = (const float*)d_in[4];
    const float* g1    = (const float*)d_in[5];
    const float* be1   = (const float*)d_in[6];
    const float* W2    = (const float*)d_in[7];
    const float* b2    = (const float*)d_in[8];
    const float* g2    = (const float*)d_in[9];
    const float* be2   = (const float*)d_in[10];
    const float* W3    = (const float*)d_in[11];
    const float* b3    = (const float*)d_in[12];

    const size_t H_BYTES = (size_t)M_TOT * HID * 2;  // 134,217,728
    if (ws_size < 2 * H_BYTES) return;               // clean fail instead of OOB crash
    char* ws = (char*)d_ws;
    unsigned short* H1 = (unsigned short*)ws;
    unsigned short* H2 = (unsigned short*)(ws + H_BYTES);

    // Small scratch lives in d_out (1.57MB) until g3 overwrites it.
    float* outf   = (float*)d_out;
    float* gbias  = outf;                        // 32768 floats
    float* sums1  = gbias + B_GRAPHS * HID;      // 1024 (sum | sumsq)
    float* sums2  = sums1 + 2 * HID;             // 1024
    float* ss1    = sums2 + 2 * HID;             // 1024
    unsigned short* W2bf = (unsigned short*)(ss1 + 2 * HID);  // 262144 shorts (512KB)
    // ss2 lives in the H1 region: written by finalize2 AFTER gemm2 consumed H1,
    // read by g3 (which writes d_out — so it can't live in d_out).
    float* ss2 = (float*)ws;

    hipMemsetAsync(sums1, 0, 2 * 2 * HID * sizeof(float), stream);

    prep_kernel<<<B_GRAPHS, 512, 0, stream>>>(x, W1, b1, gbias);
    cvt_kernel<<<(HID * HID / 8) / 256, 256, 0, stream>>>(W2, W2bf);

    gemm1_kernel<<<(M_TOT / 128) * (HID / 128), 256, 0, stream>>>(
        cond, W1, gbias, sums1, H1);
    finalize_kernel<<<1, HID, 0, stream>>>(sums1, g1, be1, ss1);
    act_kernel<<<ACT_BLOCKS, 256, 0, stream>>>(H1, ss1);

    gemm2_kernel<<<(M_TOT / 128) * (HID / 128), 256, 0, stream>>>(
        H1, W2bf, b2, sums2, H2);
    finalize_kernel<<<1, HID, 0, stream>>>(sums2, g2, be2, ss2);

    g3_kernel<<<M_TOT / 32, 256, 0, stream>>>(H2, ss2, W3, b3, outf);
}